// Round 15
// baseline (182.731 us; speedup 1.0000x reference)
//
#include <hip/hip_runtime.h>
#include <hip/hip_bf16.h>

#define DMODEL 1024
#define DH 64
#define BB 4
#define SS 2048
#define NROW (BB * SS)   // 8192
#define NS 8             // kv-splits per q-tile

typedef __attribute__((ext_vector_type(8))) short bf16x8;
typedef __attribute__((ext_vector_type(4))) float f32x4;

__device__ __forceinline__ unsigned short f2bf(float f) {
    __hip_bfloat16 h = __float2bfloat16(f);
    return __builtin_bit_cast(unsigned short, h);
}

// ---------------- prep: Wt[192][1024] bf16 = [Wq|Wk|Wv]^T ----------------
// LDS tile transpose: coalesced reads AND coalesced writes (old version did
// 2-byte scattered stores -> 64 cache-line RMWs per instruction).
__global__ __launch_bounds__(256) void prep_wt_kernel(
    const float* __restrict__ Wq, const float* __restrict__ Wk,
    const float* __restrict__ Wv, unsigned short* __restrict__ Wt)
{
    __shared__ float T[64][65];
    const int tid = threadIdx.x;
    const int m   = blockIdx.x;          // 0..2
    const int k0  = blockIdx.y * 64;     // k chunk
    const float* W = (m == 0) ? Wq : (m == 1) ? Wk : Wv;

    const int tn = tid & 63, tk = tid >> 6;
    #pragma unroll
    for (int j = 0; j < 16; ++j)         // read rows k0+4j+tk, coalesced in n
        T[4 * j + tk][tn] = W[(size_t)(k0 + 4 * j + tk) * DH + tn];
    __syncthreads();

    const int wk = tid & 63, wn = tid >> 6;
    #pragma unroll
    for (int j = 0; j < 16; ++j)         // write rows (m*64 + 4j+wn), coalesced in k
        Wt[(size_t)(m * 64 + 4 * j + wn) * DMODEL + k0 + wk] =
            f2bf(T[wk][4 * j + wn]);
}

// ---------------- QKV projection: barrier-free, gll-staged B ----------------
// (unchanged from round 14)
__global__ __launch_bounds__(256) void qkv_proj_mfma(
    const float* __restrict__ emb, const unsigned short* __restrict__ Wt,
    const float* __restrict__ bq, const float* __restrict__ bk,
    const float* __restrict__ bv,
    unsigned short* __restrict__ Q, unsigned short* __restrict__ K,
    unsigned short* __restrict__ V)
{
    __shared__ unsigned short Bs[4][3][48 * 64];   // [wave][ring][48 rows x 64 bf16]

    const int tid  = threadIdx.x;
    const int lane = tid & 63;
    const int w    = tid >> 6;
    const int wr   = w >> 1;
    const int wc   = w & 1;
    const int c    = lane & 15;
    const int g    = lane >> 4;
    const int row0    = blockIdx.x * 32 + 16 * wr;
    const int colbase = blockIdx.y * 96 + 48 * wc;

    const int bj_row = lane >> 3;
    const int bj_sl  = (lane & 7) ^ (bj_row & 7);
    const unsigned short* wt_lane =
        Wt + (size_t)(colbase + bj_row) * DMODEL + 8 * bj_sl;

    const float* arow = emb + (size_t)(row0 + c) * DMODEL + 8 * g;

    f32x4 acc[3];
    #pragma unroll
    for (int t = 0; t < 3; ++t) acc[t] = (f32x4){0.f, 0.f, 0.f, 0.f};

    float4 a0[3], a1[3], a2[3], a3[3];

#define ISSUE(S, R) do {                                                     \
    _Pragma("unroll")                                                        \
    for (int j = 0; j < 6; ++j)                                              \
        __builtin_amdgcn_global_load_lds(                                    \
            (const __attribute__((address_space(1))) void*)(                 \
                wt_lane + (size_t)8 * (j) * DMODEL + 64 * (S)),              \
            (__attribute__((address_space(3))) void*)&Bs[w][R][(j) * 512],   \
            16, 0, 0);                                                       \
    a0[R] = *reinterpret_cast<const float4*>(arow + 64 * (S));               \
    a1[R] = *reinterpret_cast<const float4*>(arow + 64 * (S) + 4);           \
    a2[R] = *reinterpret_cast<const float4*>(arow + 64 * (S) + 32);          \
    a3[R] = *reinterpret_cast<const float4*>(arow + 64 * (S) + 36);          \
} while (0)

    ISSUE(0, 0);
    ISSUE(1, 1);

    #pragma unroll
    for (int s = 0; s < 16; ++s) {
        const int r = s % 3;
        if (s < 15) asm volatile("s_waitcnt vmcnt(10)" ::: "memory");
        else        asm volatile("s_waitcnt vmcnt(0)"  ::: "memory");
        __builtin_amdgcn_sched_barrier(0);

        if (s + 2 < 16) ISSUE(s + 2, (s + 2) % 3);

        bf16x8 af[2];
        {
            union { bf16x8 v; unsigned short u[8]; } p0, p1;
            p0.u[0] = f2bf(a0[r].x); p0.u[1] = f2bf(a0[r].y);
            p0.u[2] = f2bf(a0[r].z); p0.u[3] = f2bf(a0[r].w);
            p0.u[4] = f2bf(a1[r].x); p0.u[5] = f2bf(a1[r].y);
            p0.u[6] = f2bf(a1[r].z); p0.u[7] = f2bf(a1[r].w);
            p1.u[0] = f2bf(a2[r].x); p1.u[1] = f2bf(a2[r].y);
            p1.u[2] = f2bf(a2[r].z); p1.u[3] = f2bf(a2[r].w);
            p1.u[4] = f2bf(a3[r].x); p1.u[5] = f2bf(a3[r].y);
            p1.u[6] = f2bf(a3[r].z); p1.u[7] = f2bf(a3[r].w);
            af[0] = p0.v; af[1] = p1.v;
        }

        #pragma unroll
        for (int t = 0; t < 3; ++t)
            #pragma unroll
            for (int kp = 0; kp < 2; ++kp) {
                const int lrow = 16 * t + c;
                const int slot = (4 * kp + g) ^ (lrow & 7);
                bf16x8 bfr = __builtin_bit_cast(bf16x8,
                    *reinterpret_cast<const uint4*>(&Bs[w][r][lrow * 64 + slot * 8]));
                acc[t] = __builtin_amdgcn_mfma_f32_16x16x32_bf16(af[kp], bfr, acc[t], 0, 0, 0);
            }
    }
#undef ISSUE

    #pragma unroll
    for (int t = 0; t < 3; ++t) {
        const int col = colbase + 16 * t + c;
        const int m   = col >> 6;
        const int lc  = col & 63;
        const float* bias = (m == 0) ? bq : (m == 1) ? bk : bv;
        unsigned short* O = (m == 0) ? Q : (m == 1) ? K : V;
        const float bs    = bias[lc];
        const float scale = (m == 0) ? 0.125f : 1.0f;
        #pragma unroll
        for (int i = 0; i < 4; ++i) {
            const int rr = row0 + 4 * g + i;
            O[(size_t)rr * DH + lc] = f2bf((acc[t][i] + bs) * scale);
        }
    }
}

// ------- causal flash attention, KV-split, FUSED last-block combine -------
__global__ __launch_bounds__(256) void attn_mfma_split(
    const unsigned short* __restrict__ Q, const unsigned short* __restrict__ K,
    const unsigned short* __restrict__ V,
    float* __restrict__ Opart, float* __restrict__ mpart,
    float* __restrict__ lpart, float* __restrict__ out,
    int* __restrict__ cnt)
{
    __shared__ unsigned short Ks[64][72];      // [kv][d]
    __shared__ unsigned short Vt[64][72];      // [phys_d][kv], row-swizzled
    __shared__ unsigned short Ps[4][16][72];   // per-wave P rows [q-local][kv]
    __shared__ int lastflag;

    const int tid  = threadIdx.x;
    const int lane = tid & 63;
    const int w    = tid >> 6;
    const int c    = lane & 15;
    const int g    = lane >> 4;
    const int qt   = blockIdx.x;
    const int b    = blockIdx.y;
    const int sp   = blockIdx.z;
    const int q0   = qt * 64;

    const int ntile = qt + 1;
    const int kt0 = (ntile * sp) / NS;
    const int kt1 = (ntile * (sp + 1)) / NS;

    const unsigned short* Qb = Q + (size_t)b * SS * DH;
    const unsigned short* Kb = K + (size_t)b * SS * DH;
    const unsigned short* Vb = V + (size_t)b * SS * DH;

    bf16x8 qa[2];
    #pragma unroll
    for (int kp = 0; kp < 2; ++kp)
        qa[kp] = __builtin_bit_cast(bf16x8,
            *reinterpret_cast<const uint4*>(
                &Qb[(size_t)(q0 + 16 * w + c) * DH + 32 * kp + 8 * g]));

    f32x4 o[4];   // o[t][i] = O^T[d = 16t+4g+i][q = 16w+c], unnormalized
    #pragma unroll
    for (int t = 0; t < 4; ++t) o[t] = (f32x4){0.f, 0.f, 0.f, 0.f};
    float m_i = -1e30f;
    float l_i = 0.f;

    for (int kt = kt0; kt < kt1; ++kt) {
        const int kb0 = kt * 64;
        __syncthreads();
        #pragma unroll
        for (int j = 0; j < 2; ++j) {
            const int idx = tid + 256 * j;
            const int kv  = idx >> 3;
            const int m8  = idx & 7;
            const int d0  = m8 * 8;
            *reinterpret_cast<uint4*>(&Ks[kv][d0]) =
                *reinterpret_cast<const uint4*>(&Kb[(size_t)(kb0 + kv) * DH + d0]);
            const uint4 vv =
                *reinterpret_cast<const uint4*>(&Vb[(size_t)(kb0 + kv) * DH + d0]);
            const unsigned wd[4] = {vv.x, vv.y, vv.z, vv.w};
            #pragma unroll
            for (int e = 0; e < 8; ++e)
                Vt[(d0 + e) ^ m8][kv] =
                    (unsigned short)(wd[e >> 1] >> (16 * (e & 1)));
        }
        __syncthreads();

        f32x4 s[4];
        #pragma unroll
        for (int t = 0; t < 4; ++t) s[t] = (f32x4){0.f, 0.f, 0.f, 0.f};
        #pragma unroll
        for (int t = 0; t < 4; ++t)
            #pragma unroll
            for (int kp = 0; kp < 2; ++kp) {
                bf16x8 kf = __builtin_bit_cast(bf16x8,
                    *reinterpret_cast<const uint4*>(&Ks[16 * t + c][32 * kp + 8 * g]));
                s[t] = __builtin_amdgcn_mfma_f32_16x16x32_bf16(kf, qa[kp], s[t], 0, 0, 0);
            }

        if (kt == qt) {
            #pragma unroll
            for (int t = 0; t < 4; ++t)
                #pragma unroll
                for (int i = 0; i < 4; ++i)
                    if (16 * t + 4 * g + i > 16 * w + c) s[t][i] = -1e30f;
        }

        float mx = m_i;
        #pragma unroll
        for (int t = 0; t < 4; ++t)
            mx = fmaxf(mx, fmaxf(fmaxf(s[t][0], s[t][1]), fmaxf(s[t][2], s[t][3])));
        mx = fmaxf(mx, __shfl_xor(mx, 16));
        mx = fmaxf(mx, __shfl_xor(mx, 32));
        const float al = __expf(m_i - mx);
        m_i = mx;
        float sum = 0.f;
        #pragma unroll
        for (int t = 0; t < 4; ++t)
            #pragma unroll
            for (int i = 0; i < 4; ++i) {
                const float p = __expf(s[t][i] - mx);
                s[t][i] = p;
                sum += p;
            }
        sum += __shfl_xor(sum, 16);
        sum += __shfl_xor(sum, 32);
        l_i = l_i * al + sum;

        #pragma unroll
        for (int t = 0; t < 4; ++t) {
            uint2 u;
            u.x = (unsigned)f2bf(s[t][0]) | ((unsigned)f2bf(s[t][1]) << 16);
            u.y = (unsigned)f2bf(s[t][2]) | ((unsigned)f2bf(s[t][3]) << 16);
            *reinterpret_cast<uint2*>(&Ps[w][c][16 * t + 4 * g]) = u;
        }

        #pragma unroll
        for (int t = 0; t < 4; ++t)
            #pragma unroll
            for (int i = 0; i < 4; ++i)
                o[t][i] *= al;

        #pragma unroll
        for (int kp = 0; kp < 2; ++kp) {
            bf16x8 pb = __builtin_bit_cast(bf16x8,
                *reinterpret_cast<const uint4*>(&Ps[w][c][32 * kp + 8 * g]));
            #pragma unroll
            for (int t = 0; t < 4; ++t) {
                const int dv = 16 * t + c;
                const int pr = dv ^ ((2 * t + (c >> 3)) & 7);
                bf16x8 vf = __builtin_bit_cast(bf16x8,
                    *reinterpret_cast<const uint4*>(&Vt[pr][32 * kp + 8 * g]));
                o[t] = __builtin_amdgcn_mfma_f32_16x16x32_bf16(vf, pb, o[t], 0, 0, 0);
            }
        }
    }

    // epilogue: unnormalized partials
    const int qrow = b * SS + q0 + 16 * w + c;
    #pragma unroll
    for (int t = 0; t < 4; ++t) {
        float4 v = {o[t][0], o[t][1], o[t][2], o[t][3]};
        *reinterpret_cast<float4*>(
            &Opart[((size_t)sp * NROW + qrow) * DH + 16 * t + 4 * g]) = v;
    }
    if (g == 0) {
        mpart[(size_t)sp * NROW + qrow] = m_i;
        lpart[(size_t)sp * NROW + qrow] = l_i;
    }

    // ---- last-block combine (split-k pattern) ----
    __threadfence();           // make this block's partials device-visible
    __syncthreads();
    if (tid == 0) {
        const int old = atomicAdd(&cnt[b * (SS / 64) + qt], 1);
        lastflag = (old == NS - 1);
    }
    __syncthreads();
    if (lastflag) {
        __threadfence();       // acquire: see all other blocks' partials
        #pragma unroll
        for (int it = 0; it < 4; ++it) {
            const int idx2 = tid + 256 * it;       // row-local*16 + d4
            const int r    = idx2 >> 4;
            const int d4   = (idx2 & 15) * 4;
            const int row  = b * SS + q0 + r;
            float mm[NS];
            float M = -1e30f;
            #pragma unroll
            for (int s2 = 0; s2 < NS; ++s2) {
                mm[s2] = mpart[(size_t)s2 * NROW + row];
                M = fmaxf(M, mm[s2]);
            }
            float L = 0.f;
            float4 acc = {0.f, 0.f, 0.f, 0.f};
            #pragma unroll
            for (int s2 = 0; s2 < NS; ++s2) {
                const float wgt = __expf(mm[s2] - M);
                L += wgt * lpart[(size_t)s2 * NROW + row];
                const float4 p = *reinterpret_cast<const float4*>(
                    &Opart[((size_t)s2 * NROW + row) * DH + d4]);
                acc.x += wgt * p.x; acc.y += wgt * p.y;
                acc.z += wgt * p.z; acc.w += wgt * p.w;
            }
            const float inv = 1.f / L;
            float4 res = {acc.x * inv, acc.y * inv, acc.z * inv, acc.w * inv};
            *reinterpret_cast<float4*>(&out[(size_t)row * DH + d4]) = res;
        }
    }
}

extern "C" void kernel_launch(void* const* d_in, const int* in_sizes, int n_in,
                              void* d_out, int out_size, void* d_ws, size_t ws_size,
                              hipStream_t stream) {
    const float* emb = (const float*)d_in[0];
    const float* Wq  = (const float*)d_in[1];
    const float* bq  = (const float*)d_in[2];
    const float* Wk  = (const float*)d_in[3];
    const float* bk  = (const float*)d_in[4];
    const float* Wv  = (const float*)d_in[5];
    const float* bv  = (const float*)d_in[6];
    float* out = (float*)d_out;

    unsigned short* Qw = (unsigned short*)d_ws;
    unsigned short* Kw = Qw + (size_t)NROW * DH;
    unsigned short* Vw = Kw + (size_t)NROW * DH;
    unsigned short* Wt = Vw + (size_t)NROW * DH;          // 192*1024 bf16
    float* Opart = (float*)(Wt + (size_t)192 * DMODEL);   // [NS][NROW][DH] f32
    float* mpart = Opart + (size_t)NS * NROW * DH;        // [NS][NROW]
    float* lpart = mpart + (size_t)NS * NROW;             // [NS][NROW]
    int*   cnt   = (int*)(lpart + (size_t)NS * NROW);     // [BB][SS/64]

    hipMemsetAsync(cnt, 0, BB * (SS / 64) * sizeof(int), stream);
    hipLaunchKernelGGL(prep_wt_kernel, dim3(3, 16), dim3(256), 0, stream,
                       Wq, Wk, Wv, Wt);
    hipLaunchKernelGGL(qkv_proj_mfma, dim3(NROW / 32, 2), dim3(256), 0, stream,
                       emb, Wt, bq, bk, bv, Qw, Kw, Vw);
    hipLaunchKernelGGL(attn_mfma_split, dim3(SS / 64, BB, NS), dim3(256), 0, stream,
                       Qw, Kw, Vw, Opart, mpart, lpart, out, cnt);
}

// Round 16
// 53.420 us; speedup vs baseline: 3.4206x; 3.4206x over previous
//
#include <hip/hip_runtime.h>
#include <hip/hip_bf16.h>

#define DMODEL 1024
#define DH 64
#define BB 4
#define SS 2048
#define NROW (BB * SS)   // 8192
#define NS 8             // kv-splits per q-tile

typedef __attribute__((ext_vector_type(8))) short bf16x8;
typedef __attribute__((ext_vector_type(4))) float f32x4;

__device__ __forceinline__ unsigned short f2bf(float f) {
    __hip_bfloat16 h = __float2bfloat16(f);
    return __builtin_bit_cast(unsigned short, h);
}

// ---------------- prep: Wt[192][1024] bf16 = [Wq|Wk|Wv]^T ----------------
// LDS tile transpose: coalesced reads AND coalesced writes.
__global__ __launch_bounds__(256) void prep_wt_kernel(
    const float* __restrict__ Wq, const float* __restrict__ Wk,
    const float* __restrict__ Wv, unsigned short* __restrict__ Wt)
{
    __shared__ float T[64][65];
    const int tid = threadIdx.x;
    const int m   = blockIdx.x;          // 0..2
    const int k0  = blockIdx.y * 64;     // k chunk
    const float* W = (m == 0) ? Wq : (m == 1) ? Wk : Wv;

    const int tn = tid & 63, tk = tid >> 6;
    #pragma unroll
    for (int j = 0; j < 16; ++j)         // read rows k0+4j+tk, coalesced in n
        T[4 * j + tk][tn] = W[(size_t)(k0 + 4 * j + tk) * DH + tn];
    __syncthreads();

    const int wk = tid & 63, wn = tid >> 6;
    #pragma unroll
    for (int j = 0; j < 16; ++j)         // write rows (m*64 + 4j+wn), coalesced in k
        Wt[(size_t)(m * 64 + 4 * j + wn) * DMODEL + k0 + wk] =
            f2bf(T[wk][4 * j + wn]);
}

// ---------------- QKV projection: barrier-free, gll-staged B ----------------
// (unchanged from round 14 — best measured proj)
__global__ __launch_bounds__(256) void qkv_proj_mfma(
    const float* __restrict__ emb, const unsigned short* __restrict__ Wt,
    const float* __restrict__ bq, const float* __restrict__ bk,
    const float* __restrict__ bv,
    unsigned short* __restrict__ Q, unsigned short* __restrict__ K,
    unsigned short* __restrict__ V)
{
    __shared__ unsigned short Bs[4][3][48 * 64];   // [wave][ring][48 rows x 64 bf16]

    const int tid  = threadIdx.x;
    const int lane = tid & 63;
    const int w    = tid >> 6;
    const int wr   = w >> 1;
    const int wc   = w & 1;
    const int c    = lane & 15;
    const int g    = lane >> 4;
    const int row0    = blockIdx.x * 32 + 16 * wr;
    const int colbase = blockIdx.y * 96 + 48 * wc;

    const int bj_row = lane >> 3;
    const int bj_sl  = (lane & 7) ^ (bj_row & 7);
    const unsigned short* wt_lane =
        Wt + (size_t)(colbase + bj_row) * DMODEL + 8 * bj_sl;

    const float* arow = emb + (size_t)(row0 + c) * DMODEL + 8 * g;

    f32x4 acc[3];
    #pragma unroll
    for (int t = 0; t < 3; ++t) acc[t] = (f32x4){0.f, 0.f, 0.f, 0.f};

    float4 a0[3], a1[3], a2[3], a3[3];

#define ISSUE(S, R) do {                                                     \
    _Pragma("unroll")                                                        \
    for (int j = 0; j < 6; ++j)                                              \
        __builtin_amdgcn_global_load_lds(                                    \
            (const __attribute__((address_space(1))) void*)(                 \
                wt_lane + (size_t)8 * (j) * DMODEL + 64 * (S)),              \
            (__attribute__((address_space(3))) void*)&Bs[w][R][(j) * 512],   \
            16, 0, 0);                                                       \
    a0[R] = *reinterpret_cast<const float4*>(arow + 64 * (S));               \
    a1[R] = *reinterpret_cast<const float4*>(arow + 64 * (S) + 4);           \
    a2[R] = *reinterpret_cast<const float4*>(arow + 64 * (S) + 32);          \
    a3[R] = *reinterpret_cast<const float4*>(arow + 64 * (S) + 36);          \
} while (0)

    ISSUE(0, 0);
    ISSUE(1, 1);

    #pragma unroll
    for (int s = 0; s < 16; ++s) {
        const int r = s % 3;
        if (s < 15) asm volatile("s_waitcnt vmcnt(10)" ::: "memory");
        else        asm volatile("s_waitcnt vmcnt(0)"  ::: "memory");
        __builtin_amdgcn_sched_barrier(0);

        if (s + 2 < 16) ISSUE(s + 2, (s + 2) % 3);

        bf16x8 af[2];
        {
            union { bf16x8 v; unsigned short u[8]; } p0, p1;
            p0.u[0] = f2bf(a0[r].x); p0.u[1] = f2bf(a0[r].y);
            p0.u[2] = f2bf(a0[r].z); p0.u[3] = f2bf(a0[r].w);
            p0.u[4] = f2bf(a1[r].x); p0.u[5] = f2bf(a1[r].y);
            p0.u[6] = f2bf(a1[r].z); p0.u[7] = f2bf(a1[r].w);
            p1.u[0] = f2bf(a2[r].x); p1.u[1] = f2bf(a2[r].y);
            p1.u[2] = f2bf(a2[r].z); p1.u[3] = f2bf(a2[r].w);
            p1.u[4] = f2bf(a3[r].x); p1.u[5] = f2bf(a3[r].y);
            p1.u[6] = f2bf(a3[r].z); p1.u[7] = f2bf(a3[r].w);
            af[0] = p0.v; af[1] = p1.v;
        }

        #pragma unroll
        for (int t = 0; t < 3; ++t)
            #pragma unroll
            for (int kp = 0; kp < 2; ++kp) {
                const int lrow = 16 * t + c;
                const int slot = (4 * kp + g) ^ (lrow & 7);
                bf16x8 bfr = __builtin_bit_cast(bf16x8,
                    *reinterpret_cast<const uint4*>(&Bs[w][r][lrow * 64 + slot * 8]));
                acc[t] = __builtin_amdgcn_mfma_f32_16x16x32_bf16(af[kp], bfr, acc[t], 0, 0, 0);
            }
    }
#undef ISSUE

    #pragma unroll
    for (int t = 0; t < 3; ++t) {
        const int col = colbase + 16 * t + c;
        const int m   = col >> 6;
        const int lc  = col & 63;
        const float* bias = (m == 0) ? bq : (m == 1) ? bk : bv;
        unsigned short* O = (m == 0) ? Q : (m == 1) ? K : V;
        const float bs    = bias[lc];
        const float scale = (m == 0) ? 0.125f : 1.0f;
        #pragma unroll
        for (int i = 0; i < 4; ++i) {
            const int rr = row0 + 4 * g + i;
            O[(size_t)rr * DH + lc] = f2bf((acc[t][i] + bs) * scale);
        }
    }
}

// ---------------- causal flash attention via MFMA, KV-split ----------------
// (round-13 structure: separate combine kernel, NO fences/atomics)
__global__ __launch_bounds__(256) void attn_mfma_split(
    const unsigned short* __restrict__ Q, const unsigned short* __restrict__ K,
    const unsigned short* __restrict__ V,
    float* __restrict__ Opart, float* __restrict__ mpart,
    float* __restrict__ lpart)
{
    __shared__ unsigned short Ks[64][72];      // [kv][d]
    __shared__ unsigned short Vt[64][72];      // [phys_d][kv], row-swizzled
    __shared__ unsigned short Ps[4][16][72];   // per-wave P rows [q-local][kv]

    const int tid  = threadIdx.x;
    const int lane = tid & 63;
    const int w    = tid >> 6;
    const int c    = lane & 15;
    const int g    = lane >> 4;
    const int qt   = blockIdx.x;
    const int b    = blockIdx.y;
    const int sp   = blockIdx.z;
    const int q0   = qt * 64;

    const int ntile = qt + 1;
    const int kt0 = (ntile * sp) / NS;
    const int kt1 = (ntile * (sp + 1)) / NS;

    const unsigned short* Qb = Q + (size_t)b * SS * DH;
    const unsigned short* Kb = K + (size_t)b * SS * DH;
    const unsigned short* Vb = V + (size_t)b * SS * DH;

    bf16x8 qa[2];
    #pragma unroll
    for (int kp = 0; kp < 2; ++kp)
        qa[kp] = __builtin_bit_cast(bf16x8,
            *reinterpret_cast<const uint4*>(
                &Qb[(size_t)(q0 + 16 * w + c) * DH + 32 * kp + 8 * g]));

    f32x4 o[4];   // o[t][i] = O^T[d = 16t+4g+i][q = 16w+c], unnormalized
    #pragma unroll
    for (int t = 0; t < 4; ++t) o[t] = (f32x4){0.f, 0.f, 0.f, 0.f};
    float m_i = -1e30f;
    float l_i = 0.f;

    for (int kt = kt0; kt < kt1; ++kt) {
        const int kb0 = kt * 64;
        __syncthreads();
        #pragma unroll
        for (int j = 0; j < 2; ++j) {
            const int idx = tid + 256 * j;
            const int kv  = idx >> 3;
            const int m8  = idx & 7;
            const int d0  = m8 * 8;
            *reinterpret_cast<uint4*>(&Ks[kv][d0]) =
                *reinterpret_cast<const uint4*>(&Kb[(size_t)(kb0 + kv) * DH + d0]);
            const uint4 vv =
                *reinterpret_cast<const uint4*>(&Vb[(size_t)(kb0 + kv) * DH + d0]);
            const unsigned wd[4] = {vv.x, vv.y, vv.z, vv.w};
            #pragma unroll
            for (int e = 0; e < 8; ++e)
                Vt[(d0 + e) ^ m8][kv] =
                    (unsigned short)(wd[e >> 1] >> (16 * (e & 1)));
        }
        __syncthreads();

        f32x4 s[4];
        #pragma unroll
        for (int t = 0; t < 4; ++t) s[t] = (f32x4){0.f, 0.f, 0.f, 0.f};
        #pragma unroll
        for (int t = 0; t < 4; ++t)
            #pragma unroll
            for (int kp = 0; kp < 2; ++kp) {
                bf16x8 kf = __builtin_bit_cast(bf16x8,
                    *reinterpret_cast<const uint4*>(&Ks[16 * t + c][32 * kp + 8 * g]));
                s[t] = __builtin_amdgcn_mfma_f32_16x16x32_bf16(kf, qa[kp], s[t], 0, 0, 0);
            }

        if (kt == qt) {
            #pragma unroll
            for (int t = 0; t < 4; ++t)
                #pragma unroll
                for (int i = 0; i < 4; ++i)
                    if (16 * t + 4 * g + i > 16 * w + c) s[t][i] = -1e30f;
        }

        float mx = m_i;
        #pragma unroll
        for (int t = 0; t < 4; ++t)
            mx = fmaxf(mx, fmaxf(fmaxf(s[t][0], s[t][1]), fmaxf(s[t][2], s[t][3])));
        mx = fmaxf(mx, __shfl_xor(mx, 16));
        mx = fmaxf(mx, __shfl_xor(mx, 32));
        const float al = __expf(m_i - mx);
        m_i = mx;
        float sum = 0.f;
        #pragma unroll
        for (int t = 0; t < 4; ++t)
            #pragma unroll
            for (int i = 0; i < 4; ++i) {
                const float p = __expf(s[t][i] - mx);
                s[t][i] = p;
                sum += p;
            }
        sum += __shfl_xor(sum, 16);
        sum += __shfl_xor(sum, 32);
        l_i = l_i * al + sum;

        #pragma unroll
        for (int t = 0; t < 4; ++t) {
            uint2 u;
            u.x = (unsigned)f2bf(s[t][0]) | ((unsigned)f2bf(s[t][1]) << 16);
            u.y = (unsigned)f2bf(s[t][2]) | ((unsigned)f2bf(s[t][3]) << 16);
            *reinterpret_cast<uint2*>(&Ps[w][c][16 * t + 4 * g]) = u;
        }

        #pragma unroll
        for (int t = 0; t < 4; ++t)
            #pragma unroll
            for (int i = 0; i < 4; ++i)
                o[t][i] *= al;

        #pragma unroll
        for (int kp = 0; kp < 2; ++kp) {
            bf16x8 pb = __builtin_bit_cast(bf16x8,
                *reinterpret_cast<const uint4*>(&Ps[w][c][32 * kp + 8 * g]));
            #pragma unroll
            for (int t = 0; t < 4; ++t) {
                const int dv = 16 * t + c;
                const int pr = dv ^ ((2 * t + (c >> 3)) & 7);
                bf16x8 vf = __builtin_bit_cast(bf16x8,
                    *reinterpret_cast<const uint4*>(&Vt[pr][32 * kp + 8 * g]));
                o[t] = __builtin_amdgcn_mfma_f32_16x16x32_bf16(vf, pb, o[t], 0, 0, 0);
            }
        }
    }

    const int qrow = b * SS + q0 + 16 * w + c;
    #pragma unroll
    for (int t = 0; t < 4; ++t) {
        float4 v = {o[t][0], o[t][1], o[t][2], o[t][3]};
        *reinterpret_cast<float4*>(
            &Opart[((size_t)sp * NROW + qrow) * DH + 16 * t + 4 * g]) = v;
    }
    if (g == 0) {
        mpart[(size_t)sp * NROW + qrow] = m_i;
        lpart[(size_t)sp * NROW + qrow] = l_i;
    }
}

// ---------------- combine partials ----------------
__global__ __launch_bounds__(256) void attn_combine(
    const float* __restrict__ Opart, const float* __restrict__ mpart,
    const float* __restrict__ lpart, float* __restrict__ out)
{
    const int idx = blockIdx.x * 256 + threadIdx.x;   // row*16 + d4
    const int row = idx >> 4;
    const int d4  = (idx & 15) * 4;

    float m[NS];
    float M = -1e30f;
    #pragma unroll
    for (int s = 0; s < NS; ++s) {
        m[s] = mpart[(size_t)s * NROW + row];
        M = fmaxf(M, m[s]);
    }
    float L = 0.f;
    float4 acc = {0.f, 0.f, 0.f, 0.f};
    #pragma unroll
    for (int s = 0; s < NS; ++s) {
        const float wgt = __expf(m[s] - M);
        L += wgt * lpart[(size_t)s * NROW + row];
        const float4 p = *reinterpret_cast<const float4*>(
            &Opart[((size_t)s * NROW + row) * DH + d4]);
        acc.x += wgt * p.x; acc.y += wgt * p.y;
        acc.z += wgt * p.z; acc.w += wgt * p.w;
    }
    const float inv = 1.f / L;
    float4 r = {acc.x * inv, acc.y * inv, acc.z * inv, acc.w * inv};
    *reinterpret_cast<float4*>(&out[(size_t)row * DH + d4]) = r;
}

extern "C" void kernel_launch(void* const* d_in, const int* in_sizes, int n_in,
                              void* d_out, int out_size, void* d_ws, size_t ws_size,
                              hipStream_t stream) {
    const float* emb = (const float*)d_in[0];
    const float* Wq  = (const float*)d_in[1];
    const float* bq  = (const float*)d_in[2];
    const float* Wk  = (const float*)d_in[3];
    const float* bk  = (const float*)d_in[4];
    const float* Wv  = (const float*)d_in[5];
    const float* bv  = (const float*)d_in[6];
    float* out = (float*)d_out;

    unsigned short* Qw = (unsigned short*)d_ws;
    unsigned short* Kw = Qw + (size_t)NROW * DH;
    unsigned short* Vw = Kw + (size_t)NROW * DH;
    unsigned short* Wt = Vw + (size_t)NROW * DH;          // 192*1024 bf16
    float* Opart = (float*)(Wt + (size_t)192 * DMODEL);   // [NS][NROW][DH] f32
    float* mpart = Opart + (size_t)NS * NROW * DH;        // [NS][NROW]
    float* lpart = mpart + (size_t)NS * NROW;             // [NS][NROW]

    hipLaunchKernelGGL(prep_wt_kernel, dim3(3, 16), dim3(256), 0, stream,
                       Wq, Wk, Wv, Wt);
    hipLaunchKernelGGL(qkv_proj_mfma, dim3(NROW / 32, 2), dim3(256), 0, stream,
                       emb, Wt, bq, bk, bv, Qw, Kw, Vw);
    hipLaunchKernelGGL(attn_mfma_split, dim3(SS / 64, BB, NS), dim3(256), 0, stream,
                       Qw, Kw, Vw, Opart, mpart, lpart);
    hipLaunchKernelGGL(attn_combine, dim3(NROW * 16 / 256), dim3(256), 0, stream,
                       Opart, mpart, lpart, out);
}